// Round 1
// baseline (985.274 us; speedup 1.0000x reference)
//
#include <hip/hip_runtime.h>

// ScaledDotProductAttention: B=2,H=16,S=2048,D=64, fp32 in/out.
// Outputs (concatenated in d_out): context [B,H,S,D], attn [B,H,S,S].
// mask semantics: mask!=0 -> score = -1e9 (masked out, attn -> 0).
//
// Design: one workgroup per (head bh, 64-row q-tile). 256 threads,
// 4x4 register tiling. Two passes over k-tiles:
//   pass1: compute scores (Q@K^T/8), online per-thread max/sumexp over its
//          column subset, butterfly-combine across the 16 threads of a row.
//   pass2: recompute scores, write attn = exp(s-m)/l (masked -> 0), stage P
//          in LDS, accumulate context += P @ V.
// Row mapping: r = ty + 16*i (ty = tid>>4). Score-col mapping: c = tx + 16*j
// (strided: makes LDS K-row reads 2-way-conflict-free). PV d-col mapping:
// d = 4*tx + j (contiguous: float4 V reads + coalesced stores).

#define S_LEN 2048
#define D_DIM 64
#define QB 64
#define KB 64
#define LD 68          // padded LDS leading dim (floats); 68*4B keeps 16B align
#define NKT (S_LEN / KB)

__device__ __forceinline__ void compute_scores(const float* __restrict__ sQ,
                                               const float* __restrict__ sK,
                                               int ty, int tx, float acc[4][4])
{
    #pragma unroll
    for (int i = 0; i < 4; ++i)
        #pragma unroll
        for (int j = 0; j < 4; ++j)
            acc[i][j] = 0.f;

    #pragma unroll 4
    for (int d4 = 0; d4 < D_DIM / 4; ++d4) {
        float4 qv[4], kv[4];
        #pragma unroll
        for (int i = 0; i < 4; ++i)
            qv[i] = *reinterpret_cast<const float4*>(&sQ[(ty + 16 * i) * LD + d4 * 4]);
        #pragma unroll
        for (int j = 0; j < 4; ++j)
            kv[j] = *reinterpret_cast<const float4*>(&sK[(tx + 16 * j) * LD + d4 * 4]);
        #pragma unroll
        for (int i = 0; i < 4; ++i)
            #pragma unroll
            for (int j = 0; j < 4; ++j)
                acc[i][j] += qv[i].x * kv[j].x + qv[i].y * kv[j].y
                           + qv[i].z * kv[j].z + qv[i].w * kv[j].w;
    }
}

__global__ __launch_bounds__(256, 2)
void sdpa_fp32_kernel(const float* __restrict__ Q,
                      const float* __restrict__ K,
                      const float* __restrict__ V,
                      const int* __restrict__ M,
                      float* __restrict__ ctx_out,
                      float* __restrict__ attn_out)
{
    __shared__ float sQ[QB * LD];
    __shared__ float sKP[KB * LD];   // K tile in score phase, P tile in PV phase
    __shared__ float sV[KB * LD];
    __shared__ float sM[QB];
    __shared__ float sIL[QB];

    const int tid = threadIdx.x;
    const int tx = tid & 15;
    const int ty = tid >> 4;

    const int bh = blockIdx.y;
    const int qt = blockIdx.x;
    const int q0 = qt * QB;

    const float* Qh = Q + (size_t)bh * S_LEN * D_DIM;
    const float* Kh = K + (size_t)bh * S_LEN * D_DIM;
    const float* Vh = V + (size_t)bh * S_LEN * D_DIM;
    const int*   Mh = M + (size_t)bh * S_LEN * S_LEN;
    float* Ah = attn_out + (size_t)bh * S_LEN * S_LEN;
    float* Ch = ctx_out  + (size_t)bh * S_LEN * D_DIM;

    // ---- load Q tile (64 rows x 64 f32), coalesced float4 ----
    #pragma unroll
    for (int i = 0; i < 4; ++i) {
        int f4 = tid + i * 256;
        int row = f4 >> 4, c4 = f4 & 15;
        float4 v = *reinterpret_cast<const float4*>(Qh + (q0 + row) * D_DIM + c4 * 4);
        *reinterpret_cast<float4*>(&sQ[row * LD + c4 * 4]) = v;
    }
    __syncthreads();

    // ================= pass 1: row max + sum(exp) =================
    float m[4], l[4];
    #pragma unroll
    for (int i = 0; i < 4; ++i) { m[i] = -1e30f; l[i] = 0.f; }

    for (int kt = 0; kt < NKT; ++kt) {
        #pragma unroll
        for (int i = 0; i < 4; ++i) {
            int f4 = tid + i * 256;
            int row = f4 >> 4, c4 = f4 & 15;
            float4 v = *reinterpret_cast<const float4*>(Kh + (kt * KB + row) * D_DIM + c4 * 4);
            *reinterpret_cast<float4*>(&sKP[row * LD + c4 * 4]) = v;
        }
        __syncthreads();

        float acc[4][4];
        compute_scores(sQ, sKP, ty, tx, acc);

        #pragma unroll
        for (int i = 0; i < 4; ++i) {
            const size_t r = (size_t)(q0 + ty + 16 * i);
            float s[4];
            #pragma unroll
            for (int j = 0; j < 4; ++j) {
                int msk = Mh[r * S_LEN + kt * KB + tx + 16 * j];
                s[j] = msk ? -1e30f : acc[i][j] * 0.125f;
            }
            float tm = fmaxf(fmaxf(s[0], s[1]), fmaxf(s[2], s[3]));
            float nm = fmaxf(m[i], tm);
            float sum = __expf(s[0] - nm) + __expf(s[1] - nm)
                      + __expf(s[2] - nm) + __expf(s[3] - nm);
            l[i] = l[i] * __expf(m[i] - nm) + sum;
            m[i] = nm;
        }
        __syncthreads();
    }

    // butterfly-combine (m,l) across the 16 threads (tx) owning each row
    #pragma unroll
    for (int i = 0; i < 4; ++i) {
        float mi = m[i], li = l[i];
        #pragma unroll
        for (int off = 1; off < 16; off <<= 1) {
            float om = __shfl_xor(mi, off);
            float ol = __shfl_xor(li, off);
            float nm = fmaxf(mi, om);
            li = li * __expf(mi - nm) + ol * __expf(om - nm);
            mi = nm;
        }
        if (tx == 0) {
            sM[ty + 16 * i]  = mi;
            sIL[ty + 16 * i] = (li > 0.f) ? (1.f / li) : 0.f;
        }
    }
    __syncthreads();

    // ================= pass 2: attn write + context =================
    float myM[4], myIL[4];
    #pragma unroll
    for (int i = 0; i < 4; ++i) {
        myM[i]  = sM[ty + 16 * i];
        myIL[i] = sIL[ty + 16 * i];
    }

    float ctx[4][4];
    #pragma unroll
    for (int i = 0; i < 4; ++i)
        #pragma unroll
        for (int j = 0; j < 4; ++j)
            ctx[i][j] = 0.f;

    for (int kt = 0; kt < NKT; ++kt) {
        #pragma unroll
        for (int i = 0; i < 4; ++i) {
            int f4 = tid + i * 256;
            int row = f4 >> 4, c4 = f4 & 15;
            *reinterpret_cast<float4*>(&sKP[row * LD + c4 * 4]) =
                *reinterpret_cast<const float4*>(Kh + (kt * KB + row) * D_DIM + c4 * 4);
            *reinterpret_cast<float4*>(&sV[row * LD + c4 * 4]) =
                *reinterpret_cast<const float4*>(Vh + (kt * KB + row) * D_DIM + c4 * 4);
        }
        __syncthreads();

        float acc[4][4];
        compute_scores(sQ, sKP, ty, tx, acc);

        float p[4][4];
        #pragma unroll
        for (int i = 0; i < 4; ++i) {
            const size_t r = (size_t)(q0 + ty + 16 * i);
            #pragma unroll
            for (int j = 0; j < 4; ++j) {
                int msk = Mh[r * S_LEN + kt * KB + tx + 16 * j];
                float pv = msk ? 0.f
                               : __expf(acc[i][j] * 0.125f - myM[i]) * myIL[i];
                p[i][j] = pv;
                Ah[r * S_LEN + kt * KB + tx + 16 * j] = pv;
            }
        }
        __syncthreads();   // done reading sKP as K

        #pragma unroll
        for (int i = 0; i < 4; ++i)
            #pragma unroll
            for (int j = 0; j < 4; ++j)
                sKP[(ty + 16 * i) * LD + tx + 16 * j] = p[i][j];
        __syncthreads();

        // ctx[i][j] += sum_k P[r_i][k] * V[k][4*tx+j]
        #pragma unroll 4
        for (int k4 = 0; k4 < KB / 4; ++k4) {
            float4 pr[4], vr[4];
            #pragma unroll
            for (int i = 0; i < 4; ++i)
                pr[i] = *reinterpret_cast<const float4*>(&sKP[(ty + 16 * i) * LD + k4 * 4]);
            #pragma unroll
            for (int kk = 0; kk < 4; ++kk)
                vr[kk] = *reinterpret_cast<const float4*>(&sV[(k4 * 4 + kk) * LD + tx * 4]);
            #pragma unroll
            for (int i = 0; i < 4; ++i) {
                ctx[i][0] += pr[i].x * vr[0].x + pr[i].y * vr[1].x + pr[i].z * vr[2].x + pr[i].w * vr[3].x;
                ctx[i][1] += pr[i].x * vr[0].y + pr[i].y * vr[1].y + pr[i].z * vr[2].y + pr[i].w * vr[3].y;
                ctx[i][2] += pr[i].x * vr[0].z + pr[i].y * vr[1].z + pr[i].z * vr[2].z + pr[i].w * vr[3].z;
                ctx[i][3] += pr[i].x * vr[0].w + pr[i].y * vr[1].w + pr[i].z * vr[2].w + pr[i].w * vr[3].w;
            }
        }
        __syncthreads();
    }

    #pragma unroll
    for (int i = 0; i < 4; ++i) {
        float4 o = make_float4(ctx[i][0], ctx[i][1], ctx[i][2], ctx[i][3]);
        *reinterpret_cast<float4*>(Ch + (size_t)(q0 + ty + 16 * i) * D_DIM + tx * 4) = o;
    }
}

extern "C" void kernel_launch(void* const* d_in, const int* in_sizes, int n_in,
                              void* d_out, int out_size, void* d_ws, size_t ws_size,
                              hipStream_t stream)
{
    const float* Q = (const float*)d_in[0];
    const float* K = (const float*)d_in[1];
    const float* V = (const float*)d_in[2];
    const int*   M = (const int*)d_in[3];

    float* ctx  = (float*)d_out;
    float* attn = ctx + (size_t)2 * 16 * S_LEN * D_DIM;  // context first, then attn

    dim3 grid(S_LEN / QB, 2 * 16);
    sdpa_fp32_kernel<<<grid, 256, 0, stream>>>(Q, K, V, M, ctx, attn);
}

// Round 2
// 656.378 us; speedup vs baseline: 1.5011x; 1.5011x over previous
//
#include <hip/hip_runtime.h>

// ScaledDotProductAttention: B=2,H=16,S=2048,D=64, fp32 in/out.
// Outputs: context [B,H,S,D] then attn [B,H,S,S], concatenated in d_out.
//
// R2: MFMA (bf16 16x16x32) for QK^T and PV; mask fetched ONCE (pass-1
// ballots stored as a 16KB LDS bitmask, re-used in pass 2).
// One workgroup = 64 q-rows x full K sweep; 4 waves, wave w owns q-rows
// [16w,16w+16). C/D layout (verified m89): D[4*(lane>>4)+reg][lane&15].
// A-frag: lane holds A[lane&15][(lane>>4)*8 + j]; B-frag: B[(lane>>4)*8+j][lane&15].

#define S_LEN 2048
#define D_DIM 64
#define QB 64
#define KB 64
#define NKT (S_LEN / KB)
#define QPAD 72   // bf16 elems per LDS row -> 144B stride: 16B aligned, 2-way banks

typedef __attribute__((ext_vector_type(8))) short bf16x8;
typedef __attribute__((ext_vector_type(4))) float f32x4;
typedef __attribute__((ext_vector_type(4))) unsigned short us4;

__device__ __forceinline__ unsigned short f2bf(float f) {
    unsigned u = __builtin_bit_cast(unsigned, f);
    u += 0x7fffu + ((u >> 16) & 1u);       // RNE
    return (unsigned short)(u >> 16);
}

__device__ __forceinline__ bf16x8 ldfrag(const unsigned short* p) {
    return *reinterpret_cast<const bf16x8*>(p);
}

// stage a 64x64 f32 tile (row stride D_DIM) into LDS bf16 [64][QPAD]
__device__ __forceinline__ void stage_bf16(const float* __restrict__ src,
                                           unsigned short* dst, int tid)
{
    #pragma unroll
    for (int i = 0; i < 4; ++i) {
        int f4 = tid + i * 256;
        int row = f4 >> 4, c4 = f4 & 15;
        float4 v = *reinterpret_cast<const float4*>(src + row * D_DIM + c4 * 4);
        us4 b = { f2bf(v.x), f2bf(v.y), f2bf(v.z), f2bf(v.w) };
        *reinterpret_cast<us4*>(&dst[row * QPAD + c4 * 4]) = b;
    }
}

__global__ __launch_bounds__(256, 3)
void sdpa_mfma_kernel(const float* __restrict__ Q,
                      const float* __restrict__ K,
                      const float* __restrict__ V,
                      const int* __restrict__ M,
                      float* __restrict__ ctx_out,
                      float* __restrict__ attn_out)
{
    __shared__ unsigned short sQ[QB * QPAD];
    __shared__ unsigned short sK[KB * QPAD];
    __shared__ unsigned short sVt[D_DIM * QPAD];      // [d][k] transposed V tile
    __shared__ unsigned short sP[4][16 * QPAD];       // per-wave P tile (16 x 64)
    __shared__ unsigned long long sBM[NKT][4][4][4];  // [kt][wave][jt][reg] ballots
    __shared__ float sM[QB], sIL[QB];

    const int tid  = threadIdx.x;
    const int lane = tid & 63;
    const int w    = tid >> 6;     // wave id 0..3
    const int lq   = lane & 15;
    const int h    = lane >> 4;    // wave quarter 0..3

    // XCD-aware swizzle: consecutive swz share bh -> same-XCD K/V L2 reuse
    int b   = blockIdx.x;
    int swz = (b & 7) * (1024 / 8) + (b >> 3);
    int bh  = swz >> 5;
    int qt  = swz & 31;
    const int q0 = qt * QB;

    const float* Qh = Q + (size_t)bh * S_LEN * D_DIM;
    const float* Kh = K + (size_t)bh * S_LEN * D_DIM;
    const float* Vh = V + (size_t)bh * S_LEN * D_DIM;
    const int*   Mh = M + (size_t)bh * S_LEN * S_LEN;
    float* Ah = attn_out + (size_t)bh * S_LEN * S_LEN;
    float* Ch = ctx_out  + (size_t)bh * S_LEN * D_DIM;

    stage_bf16(Qh + (size_t)q0 * D_DIM, sQ, tid);
    __syncthreads();

    // Q A-fragments, hoisted for the whole kernel: rows 16w+lq, d-chunks 0/1
    bf16x8 aq0 = ldfrag(&sQ[(w * 16 + lq) * QPAD + h * 8]);
    bf16x8 aq1 = ldfrag(&sQ[(w * 16 + lq) * QPAD + 32 + h * 8]);

    // ================= pass 1: row max + sum(exp), build bitmask ============
    float m[4], lsum[4];
    #pragma unroll
    for (int r = 0; r < 4; ++r) { m[r] = -1e30f; lsum[r] = 0.f; }

    for (int kt = 0; kt < NKT; ++kt) {
        stage_bf16(Kh + (size_t)(kt * KB) * D_DIM, sK, tid);
        __syncthreads();

        f32x4 acc[4];
        #pragma unroll
        for (int jt = 0; jt < 4; ++jt) {
            acc[jt] = (f32x4){0.f, 0.f, 0.f, 0.f};
            const unsigned short* kb = &sK[(jt * 16 + lq) * QPAD];
            bf16x8 b0 = ldfrag(kb + h * 8);
            bf16x8 b1 = ldfrag(kb + 32 + h * 8);
            acc[jt] = __builtin_amdgcn_mfma_f32_16x16x32_bf16(aq0, b0, acc[jt], 0, 0, 0);
            acc[jt] = __builtin_amdgcn_mfma_f32_16x16x32_bf16(aq1, b1, acc[jt], 0, 0, 0);
        }

        const int* Mrow = Mh + (size_t)(q0 + w * 16 + h * 4) * S_LEN + kt * KB;
        float sc[4][4];
        #pragma unroll
        for (int jt = 0; jt < 4; ++jt)
            #pragma unroll
            for (int r = 0; r < 4; ++r) {
                int msk = Mrow[(size_t)r * S_LEN + jt * 16 + lq];
                unsigned long long bm = __ballot(msk != 0);
                if (lane == 0) sBM[kt][w][jt][r] = bm;
                sc[jt][r] = msk ? -1e30f : acc[jt][r] * 0.125f;
            }

        #pragma unroll
        for (int r = 0; r < 4; ++r) {
            float tm = fmaxf(fmaxf(sc[0][r], sc[1][r]), fmaxf(sc[2][r], sc[3][r]));
            float nm = fmaxf(m[r], tm);
            float su = __expf(sc[0][r] - nm) + __expf(sc[1][r] - nm)
                     + __expf(sc[2][r] - nm) + __expf(sc[3][r] - nm);
            lsum[r] = lsum[r] * __expf(m[r] - nm) + su;
            m[r] = nm;
        }
        __syncthreads();
    }

    // butterfly-combine (m,l) across the 16 lanes (lq) owning each row
    #pragma unroll
    for (int r = 0; r < 4; ++r) {
        float mi = m[r], li = lsum[r];
        #pragma unroll
        for (int off = 1; off < 16; off <<= 1) {
            float om = __shfl_xor(mi, off);
            float ol = __shfl_xor(li, off);
            float nm = fmaxf(mi, om);
            li = li * __expf(mi - nm) + ol * __expf(om - nm);
            mi = nm;
        }
        if (lq == 0) {
            sM[w * 16 + h * 4 + r]  = mi;
            sIL[w * 16 + h * 4 + r] = (li > 0.f) ? (1.f / li) : 0.f;
        }
    }
    __syncthreads();

    float myM[4], myIL[4];
    #pragma unroll
    for (int r = 0; r < 4; ++r) {
        myM[r]  = sM[w * 16 + h * 4 + r];
        myIL[r] = sIL[w * 16 + h * 4 + r];
    }

    // ================= pass 2: attn write + PV ==============================
    f32x4 ctxa[4];
    #pragma unroll
    for (int dt = 0; dt < 4; ++dt) ctxa[dt] = (f32x4){0.f, 0.f, 0.f, 0.f};

    unsigned short* sPw = sP[w];

    for (int kt = 0; kt < NKT; ++kt) {
        stage_bf16(Kh + (size_t)(kt * KB) * D_DIM, sK, tid);
        // stage V transposed: sVt[d][k], coalesced scalar loads along d
        {
            const int d = tid & 63;
            const int kq = (tid >> 6) * 4;
            #pragma unroll
            for (int kk = 0; kk < KB; kk += 16) {
                int k0 = kk + kq;
                const float* vp = Vh + (size_t)(kt * KB + k0) * D_DIM + d;
                us4 bv = { f2bf(vp[0]), f2bf(vp[D_DIM]),
                           f2bf(vp[2 * D_DIM]), f2bf(vp[3 * D_DIM]) };
                *reinterpret_cast<us4*>(&sVt[d * QPAD + k0]) = bv;
            }
        }
        __syncthreads();

        f32x4 acc[4];
        #pragma unroll
        for (int jt = 0; jt < 4; ++jt) {
            acc[jt] = (f32x4){0.f, 0.f, 0.f, 0.f};
            const unsigned short* kb = &sK[(jt * 16 + lq) * QPAD];
            bf16x8 b0 = ldfrag(kb + h * 8);
            bf16x8 b1 = ldfrag(kb + 32 + h * 8);
            acc[jt] = __builtin_amdgcn_mfma_f32_16x16x32_bf16(aq0, b0, acc[jt], 0, 0, 0);
            acc[jt] = __builtin_amdgcn_mfma_f32_16x16x32_bf16(aq1, b1, acc[jt], 0, 0, 0);
        }

        float* Arow = Ah + (size_t)(q0 + w * 16 + h * 4) * S_LEN + kt * KB;
        #pragma unroll
        for (int jt = 0; jt < 4; ++jt) {
            #pragma unroll
            for (int r = 0; r < 4; ++r) {
                unsigned long long bm = sBM[kt][w][jt][r];
                bool msk = (bm >> lane) & 1ull;
                float p = msk ? 0.f
                              : __expf(acc[jt][r] * 0.125f - myM[r]) * myIL[r];
                Arow[(size_t)r * S_LEN + jt * 16 + lq] = p;
                sPw[(h * 4 + r) * QPAD + jt * 16 + lq] = f2bf(p);
            }
        }

        // per-wave P tile: ensure ds_writes complete before frag reads
        asm volatile("s_waitcnt lgkmcnt(0)" ::: "memory");

        bf16x8 pa0 = ldfrag(&sPw[lq * QPAD + h * 8]);
        bf16x8 pa1 = ldfrag(&sPw[lq * QPAD + 32 + h * 8]);
        #pragma unroll
        for (int dt = 0; dt < 4; ++dt) {
            const unsigned short* vb = &sVt[(dt * 16 + lq) * QPAD];
            bf16x8 b0 = ldfrag(vb + h * 8);
            bf16x8 b1 = ldfrag(vb + 32 + h * 8);
            ctxa[dt] = __builtin_amdgcn_mfma_f32_16x16x32_bf16(pa0, b0, ctxa[dt], 0, 0, 0);
            ctxa[dt] = __builtin_amdgcn_mfma_f32_16x16x32_bf16(pa1, b1, ctxa[dt], 0, 0, 0);
        }
        __syncthreads();
    }

    float* Crow = Ch + (size_t)(q0 + w * 16 + h * 4) * D_DIM;
    #pragma unroll
    for (int dt = 0; dt < 4; ++dt)
        #pragma unroll
        for (int r = 0; r < 4; ++r)
            Crow[(size_t)r * D_DIM + dt * 16 + lq] = ctxa[dt][r];
}

extern "C" void kernel_launch(void* const* d_in, const int* in_sizes, int n_in,
                              void* d_out, int out_size, void* d_ws, size_t ws_size,
                              hipStream_t stream)
{
    const float* Q = (const float*)d_in[0];
    const float* K = (const float*)d_in[1];
    const float* V = (const float*)d_in[2];
    const int*   M = (const int*)d_in[3];

    float* ctx  = (float*)d_out;
    float* attn = ctx + (size_t)2 * 16 * S_LEN * D_DIM;

    sdpa_mfma_kernel<<<dim3(1024), 256, 0, stream>>>(Q, K, V, M, ctx, attn);
}

// Round 3
// 471.235 us; speedup vs baseline: 2.0908x; 1.3929x over previous
//
#include <hip/hip_runtime.h>

// ScaledDotProductAttention: B=2,H=16,S=2048,D=64, fp32 in/out.
// Outputs: context [B,H,S,D] then attn [B,H,S,S], concatenated in d_out.
//
// R3: latency-focused rework of the R2 MFMA kernel.
//  - mask bitmask moved from LDS (16KB sBM) to 16 VGPRs/thread
//    (bits[jt][r], bit kt) -> LDS 37.4KB -> 4 blocks/CU (was 2).
//  - register prefetch of next K (+V) tile at loop top; convert+ds_write
//    after the post-compute barrier (T14 async-STAGE pattern).
//  - attn written coalesced (dwordx4) from the per-wave bf16 P tile.
//  - 1/8 scale folded into Q staging (exact power of two).

#define S_LEN 2048
#define D_DIM 64
#define QB 64
#define KB 64
#define NKT (S_LEN / KB)
#define QPAD 72   // bf16 elems per LDS row -> 144B stride, 16B aligned

typedef __attribute__((ext_vector_type(8))) short bf16x8;
typedef __attribute__((ext_vector_type(4))) float f32x4;
typedef __attribute__((ext_vector_type(4))) unsigned short us4;

__device__ __forceinline__ unsigned short f2bf(float f) {
    unsigned u = __builtin_bit_cast(unsigned, f);
    u += 0x7fffu + ((u >> 16) & 1u);       // RNE
    return (unsigned short)(u >> 16);
}
__device__ __forceinline__ float bf2f(unsigned short b) {
    unsigned u = (unsigned)b << 16;
    return __builtin_bit_cast(float, u);
}
__device__ __forceinline__ bf16x8 ldfrag(const unsigned short* p) {
    return *reinterpret_cast<const bf16x8*>(p);
}

__global__ __launch_bounds__(256, 4)
void sdpa_mfma_kernel(const float* __restrict__ Q,
                      const float* __restrict__ K,
                      const float* __restrict__ V,
                      const int* __restrict__ M,
                      float* __restrict__ ctx_out,
                      float* __restrict__ attn_out)
{
    __shared__ unsigned short sQ[QB * QPAD];
    __shared__ unsigned short sK[KB * QPAD];
    __shared__ unsigned short sVt[D_DIM * QPAD];   // [d][k]
    __shared__ unsigned short sP[4][16 * QPAD];    // per-wave P tile (16 x 64)
    __shared__ float sM[QB], sIL[QB];

    const int tid  = threadIdx.x;
    const int lane = tid & 63;
    const int w    = tid >> 6;
    const int lq   = lane & 15;
    const int h    = lane >> 4;

    int b   = blockIdx.x;
    int swz = (b & 7) * (1024 / 8) + (b >> 3);
    int bh  = swz >> 5;
    int qt  = swz & 31;
    const int q0 = qt * QB;

    const float* Qh = Q + (size_t)bh * S_LEN * D_DIM;
    const float* Kh = K + (size_t)bh * S_LEN * D_DIM;
    const float* Vh = V + (size_t)bh * S_LEN * D_DIM;
    const int*   Mh = M + (size_t)bh * S_LEN * S_LEN;
    float* Ah = attn_out + (size_t)bh * S_LEN * S_LEN;
    float* Ch = ctx_out  + (size_t)bh * S_LEN * D_DIM;

    // staging thread mapping (shared by Q/K): row = f4>>4, col4 = f4&15
    const int srow = tid >> 4;          // f4 = tid + i*256 -> rows srow + i*16
    const int sc4  = tid & 15;

    // ---- stage Q (scaled by 1/8) ----
    #pragma unroll
    for (int i = 0; i < 4; ++i) {
        int row = srow + i * 16;
        float4 v = *reinterpret_cast<const float4*>(Qh + (size_t)(q0 + row) * D_DIM + sc4 * 4);
        us4 bq = { f2bf(v.x * 0.125f), f2bf(v.y * 0.125f),
                   f2bf(v.z * 0.125f), f2bf(v.w * 0.125f) };
        *reinterpret_cast<us4*>(&sQ[row * QPAD + sc4 * 4]) = bq;
    }
    // ---- stage K tile 0 (direct) ----
    #pragma unroll
    for (int i = 0; i < 4; ++i) {
        int row = srow + i * 16;
        float4 v = *reinterpret_cast<const float4*>(Kh + (size_t)row * D_DIM + sc4 * 4);
        us4 bk = { f2bf(v.x), f2bf(v.y), f2bf(v.z), f2bf(v.w) };
        *reinterpret_cast<us4*>(&sK[row * QPAD + sc4 * 4]) = bk;
    }
    __syncthreads();

    bf16x8 aq0 = ldfrag(&sQ[(w * 16 + lq) * QPAD + h * 8]);
    bf16x8 aq1 = ldfrag(&sQ[(w * 16 + lq) * QPAD + 32 + h * 8]);

    // ================= pass 1: row max + sum(exp), build reg bitmask ========
    float m[4], lsum[4];
    unsigned bits[4][4];
    #pragma unroll
    for (int r = 0; r < 4; ++r) {
        m[r] = -1e30f; lsum[r] = 0.f;
        #pragma unroll
        for (int jt = 0; jt < 4; ++jt) bits[jt][r] = 0u;
    }

    for (int kt = 0; kt < NKT; ++kt) {
        // prefetch next K tile into registers
        const int ktn = (kt + 1 < NKT) ? kt + 1 : kt;
        float4 kf[4];
        #pragma unroll
        for (int i = 0; i < 4; ++i)
            kf[i] = *reinterpret_cast<const float4*>(
                Kh + (size_t)(ktn * KB + srow + i * 16) * D_DIM + sc4 * 4);

        f32x4 acc[4];
        #pragma unroll
        for (int jt = 0; jt < 4; ++jt) {
            acc[jt] = (f32x4){0.f, 0.f, 0.f, 0.f};
            const unsigned short* kb = &sK[(jt * 16 + lq) * QPAD];
            bf16x8 b0 = ldfrag(kb + h * 8);
            bf16x8 b1 = ldfrag(kb + 32 + h * 8);
            acc[jt] = __builtin_amdgcn_mfma_f32_16x16x32_bf16(aq0, b0, acc[jt], 0, 0, 0);
            acc[jt] = __builtin_amdgcn_mfma_f32_16x16x32_bf16(aq1, b1, acc[jt], 0, 0, 0);
        }

        const int* Mrow = Mh + (size_t)(q0 + w * 16 + h * 4) * S_LEN + kt * KB;
        float sc[4][4];
        #pragma unroll
        for (int jt = 0; jt < 4; ++jt)
            #pragma unroll
            for (int r = 0; r < 4; ++r) {
                int msk = Mrow[(size_t)r * S_LEN + jt * 16 + lq];
                bits[jt][r] |= (msk ? 1u : 0u) << kt;
                sc[jt][r] = msk ? -1e30f : acc[jt][r];
            }

        #pragma unroll
        for (int r = 0; r < 4; ++r) {
            float tm = fmaxf(fmaxf(sc[0][r], sc[1][r]), fmaxf(sc[2][r], sc[3][r]));
            float nm = fmaxf(m[r], tm);
            float su = __expf(sc[0][r] - nm) + __expf(sc[1][r] - nm)
                     + __expf(sc[2][r] - nm) + __expf(sc[3][r] - nm);
            lsum[r] = lsum[r] * __expf(m[r] - nm) + su;
            m[r] = nm;
        }

        if (kt + 1 < NKT) {
            __syncthreads();      // all reads of sK done
            #pragma unroll
            for (int i = 0; i < 4; ++i) {
                us4 bk = { f2bf(kf[i].x), f2bf(kf[i].y), f2bf(kf[i].z), f2bf(kf[i].w) };
                *reinterpret_cast<us4*>(&sK[(srow + i * 16) * QPAD + sc4 * 4]) = bk;
            }
            __syncthreads();      // next tile ready
        }
    }

    // butterfly-combine (m,l) across the 16 lanes owning each row
    #pragma unroll
    for (int r = 0; r < 4; ++r) {
        float mi = m[r], li = lsum[r];
        #pragma unroll
        for (int off = 1; off < 16; off <<= 1) {
            float om = __shfl_xor(mi, off);
            float ol = __shfl_xor(li, off);
            float nm = fmaxf(mi, om);
            li = li * __expf(mi - nm) + ol * __expf(om - nm);
            mi = nm;
        }
        if (lq == 0) {
            sM[w * 16 + h * 4 + r]  = mi;
            sIL[w * 16 + h * 4 + r] = (li > 0.f) ? (1.f / li) : 0.f;
        }
    }
    __syncthreads();

    float myM[4], myIL[4];
    #pragma unroll
    for (int r = 0; r < 4; ++r) {
        myM[r]  = sM[w * 16 + h * 4 + r];
        myIL[r] = sIL[w * 16 + h * 4 + r];
    }

    // ---- pass-2 prologue: stage K0 + V0 direct ----
    #pragma unroll
    for (int i = 0; i < 4; ++i) {
        int row = srow + i * 16;
        float4 v = *reinterpret_cast<const float4*>(Kh + (size_t)row * D_DIM + sc4 * 4);
        us4 bk = { f2bf(v.x), f2bf(v.y), f2bf(v.z), f2bf(v.w) };
        *reinterpret_cast<us4*>(&sK[row * QPAD + sc4 * 4]) = bk;
    }
    {
        const int d  = tid & 63;
        const int kq = (tid >> 6) * 4;
        #pragma unroll
        for (int kk = 0; kk < KB; kk += 16) {
            int k0 = kk + kq;
            const float* vp = Vh + (size_t)k0 * D_DIM + d;
            us4 bv = { f2bf(vp[0]), f2bf(vp[D_DIM]),
                       f2bf(vp[2 * D_DIM]), f2bf(vp[3 * D_DIM]) };
            *reinterpret_cast<us4*>(&sVt[d * QPAD + k0]) = bv;
        }
    }
    __syncthreads();

    // ================= pass 2: attn write + PV ==============================
    f32x4 ctxa[4];
    #pragma unroll
    for (int dt = 0; dt < 4; ++dt) ctxa[dt] = (f32x4){0.f, 0.f, 0.f, 0.f};

    unsigned short* sPw = sP[w];
    const int vd  = tid & 63;
    const int vkq = (tid >> 6) * 4;

    for (int kt = 0; kt < NKT; ++kt) {
        const int ktn = (kt + 1 < NKT) ? kt + 1 : kt;
        // prefetch next K + V tiles into registers
        float4 kf[4];
        #pragma unroll
        for (int i = 0; i < 4; ++i)
            kf[i] = *reinterpret_cast<const float4*>(
                Kh + (size_t)(ktn * KB + srow + i * 16) * D_DIM + sc4 * 4);
        float vf[4][4];
        #pragma unroll
        for (int kk = 0; kk < 4; ++kk) {
            const float* vp = Vh + (size_t)(ktn * KB + kk * 16 + vkq) * D_DIM + vd;
            #pragma unroll
            for (int e = 0; e < 4; ++e) vf[kk][e] = vp[(size_t)e * D_DIM];
        }

        f32x4 acc[4];
        #pragma unroll
        for (int jt = 0; jt < 4; ++jt) {
            acc[jt] = (f32x4){0.f, 0.f, 0.f, 0.f};
            const unsigned short* kb = &sK[(jt * 16 + lq) * QPAD];
            bf16x8 b0 = ldfrag(kb + h * 8);
            bf16x8 b1 = ldfrag(kb + 32 + h * 8);
            acc[jt] = __builtin_amdgcn_mfma_f32_16x16x32_bf16(aq0, b0, acc[jt], 0, 0, 0);
            acc[jt] = __builtin_amdgcn_mfma_f32_16x16x32_bf16(aq1, b1, acc[jt], 0, 0, 0);
        }

        #pragma unroll
        for (int jt = 0; jt < 4; ++jt)
            #pragma unroll
            for (int r = 0; r < 4; ++r) {
                bool msk = (bits[jt][r] >> kt) & 1u;
                float p = msk ? 0.f : __expf(acc[jt][r] - myM[r]) * myIL[r];
                sPw[(h * 4 + r) * QPAD + jt * 16 + lq] = f2bf(p);
            }

        // wave-local: P writes must land before P reads below
        asm volatile("s_waitcnt lgkmcnt(0)" ::: "memory");

        // coalesced attn write from sP (bf16 -> f32, dwordx4)
        {
            float* Aw = Ah + (size_t)(q0 + w * 16) * S_LEN + kt * KB;
            #pragma unroll
            for (int it = 0; it < 4; ++it) {
                int flat = it * 64 + lane;
                int row = flat >> 4, colq = flat & 15;
                us4 pb = *reinterpret_cast<const us4*>(&sPw[row * QPAD + colq * 4]);
                float4 pf = make_float4(bf2f(pb.x), bf2f(pb.y), bf2f(pb.z), bf2f(pb.w));
                *reinterpret_cast<float4*>(Aw + (size_t)row * S_LEN + colq * 4) = pf;
            }
        }

        bf16x8 pa0 = ldfrag(&sPw[lq * QPAD + h * 8]);
        bf16x8 pa1 = ldfrag(&sPw[lq * QPAD + 32 + h * 8]);
        #pragma unroll
        for (int dt = 0; dt < 4; ++dt) {
            const unsigned short* vb = &sVt[(dt * 16 + lq) * QPAD];
            bf16x8 b0 = ldfrag(vb + h * 8);
            bf16x8 b1 = ldfrag(vb + 32 + h * 8);
            ctxa[dt] = __builtin_amdgcn_mfma_f32_16x16x32_bf16(pa0, b0, ctxa[dt], 0, 0, 0);
            ctxa[dt] = __builtin_amdgcn_mfma_f32_16x16x32_bf16(pa1, b1, ctxa[dt], 0, 0, 0);
        }

        if (kt + 1 < NKT) {
            __syncthreads();      // all reads of sK/sVt done
            #pragma unroll
            for (int i = 0; i < 4; ++i) {
                us4 bk = { f2bf(kf[i].x), f2bf(kf[i].y), f2bf(kf[i].z), f2bf(kf[i].w) };
                *reinterpret_cast<us4*>(&sK[(srow + i * 16) * QPAD + sc4 * 4]) = bk;
            }
            #pragma unroll
            for (int kk = 0; kk < 4; ++kk) {
                us4 bv = { f2bf(vf[kk][0]), f2bf(vf[kk][1]),
                           f2bf(vf[kk][2]), f2bf(vf[kk][3]) };
                *reinterpret_cast<us4*>(&sVt[vd * QPAD + kk * 16 + vkq]) = bv;
            }
            __syncthreads();      // next tile ready
        }
    }

    float* Crow = Ch + (size_t)(q0 + w * 16 + h * 4) * D_DIM;
    #pragma unroll
    for (int dt = 0; dt < 4; ++dt)
        #pragma unroll
        for (int r = 0; r < 4; ++r)
            Crow[(size_t)r * D_DIM + dt * 16 + lq] = ctxa[dt][r];
}

extern "C" void kernel_launch(void* const* d_in, const int* in_sizes, int n_in,
                              void* d_out, int out_size, void* d_ws, size_t ws_size,
                              hipStream_t stream)
{
    const float* Q = (const float*)d_in[0];
    const float* K = (const float*)d_in[1];
    const float* V = (const float*)d_in[2];
    const int*   M = (const int*)d_in[3];

    float* ctx  = (float*)d_out;
    float* attn = ctx + (size_t)2 * 16 * S_LEN * D_DIM;

    sdpa_mfma_kernel<<<dim3(1024), 256, 0, stream>>>(Q, K, V, M, ctx, attn);
}

// Round 4
// 323.946 us; speedup vs baseline: 3.0415x; 1.4547x over previous
//
#include <hip/hip_runtime.h>

// ScaledDotProductAttention: B=2,H=16,S=2048,D=64, fp32 in/out.
// Outputs: context [B,H,S,D] then attn [B,H,S,S], concatenated in d_out.
//
// R4: prep kernel pre-converts K,V -> bf16 8KB tiles in d_ws, XOR-swizzled
// ((chunk16 ^ (row&7)) within each 128B row) and V transposed ([d][k]).
// Main kernel stages tiles with global_load_lds (16B, zero VALU), K/V
// double-buffered, ONE barrier per k-iteration. Mask fetched once (pass 1)
// with +1-ahead register prefetch; bits kept in 16 VGPRs for pass 2.
// LDS exactly 40960B -> 4 blocks/CU. Scores in log2 domain (exp2).

#define S_LEN 2048
#define D_DIM 64
#define NKT 32
#define QB 64

typedef __attribute__((ext_vector_type(8))) short bf16x8;
typedef __attribute__((ext_vector_type(4))) float f32x4;
typedef __attribute__((ext_vector_type(4))) unsigned short us4;

__device__ __forceinline__ unsigned short f2bf(float f) {
    unsigned u = __builtin_bit_cast(unsigned, f);
    u += 0x7fffu + ((u >> 16) & 1u);       // RNE
    return (unsigned short)(u >> 16);
}
__device__ __forceinline__ float bf2f(unsigned short b) {
    return __builtin_bit_cast(float, (unsigned)b << 16);
}

typedef const __attribute__((address_space(1))) void cg_void;
typedef __attribute__((address_space(3))) void lds_void;
__device__ __forceinline__ void gload16(const void* g, void* l) {
    __builtin_amdgcn_global_load_lds((cg_void*)g, (lds_void*)l, 16, 0, 0);
}

// ---------------- prep: K,V f32 -> swizzled bf16 tiles in ws ----------------
__global__ __launch_bounds__(256)
void sdpa_prep(const float* __restrict__ K, const float* __restrict__ V,
               unsigned short* __restrict__ Kimg, unsigned short* __restrict__ Vimg)
{
    const int blk = blockIdx.x;          // bh*32 + kt
    const int bh = blk >> 5, kt = blk & 31;
    const float* Kt = K + ((size_t)bh * S_LEN + kt * 64) * D_DIM;
    const float* Vt = V + ((size_t)bh * S_LEN + kt * 64) * D_DIM;
    unsigned char* Kd = (unsigned char*)(Kimg + (size_t)blk * 4096);
    unsigned char* Vd = (unsigned char*)(Vimg + (size_t)blk * 4096);
    const int tid = threadIdx.x;

    // K tile: element (row, c) at byte row*128 + ((c16^(row&7))<<4) + (c&7)*2
    {
        const int srow = tid >> 4, c4 = tid & 15;
        #pragma unroll
        for (int i = 0; i < 4; ++i) {
            int row = srow + i * 16;
            float4 v = *(const float4*)(Kt + (size_t)row * D_DIM + c4 * 4);
            us4 b = { f2bf(v.x), f2bf(v.y), f2bf(v.z), f2bf(v.w) };
            *(us4*)(Kd + row * 128 + (((c4 >> 1) ^ (row & 7)) << 4) + (c4 & 1) * 8) = b;
        }
    }
    // V tile transposed: Vimg element (d, k) = V[k][d]
    {
        const int d = tid & 63, kg = tid >> 6;
        #pragma unroll
        for (int kk = 0; kk < 4; ++kk) {
            int k4 = kg * 4 + kk;        // 0..15
            int k0 = k4 * 4;
            float v0 = Vt[(size_t)(k0 + 0) * D_DIM + d];
            float v1 = Vt[(size_t)(k0 + 1) * D_DIM + d];
            float v2 = Vt[(size_t)(k0 + 2) * D_DIM + d];
            float v3 = Vt[(size_t)(k0 + 3) * D_DIM + d];
            us4 b = { f2bf(v0), f2bf(v1), f2bf(v2), f2bf(v3) };
            *(us4*)(Vd + d * 128 + (((k4 >> 1) ^ (d & 7)) << 4) + (k4 & 1) * 8) = b;
        }
    }
}

// ------------------------------- main ---------------------------------------
__global__ __launch_bounds__(256, 4)
void sdpa_main(const float* __restrict__ Q,
               const int* __restrict__ M,
               const unsigned short* __restrict__ Kimg,
               const unsigned short* __restrict__ Vimg,
               float* __restrict__ ctx_out,
               float* __restrict__ attn_out)
{
    __shared__ __align__(16) unsigned char smem[40960];
    unsigned short* const sK0 = (unsigned short*)(smem);
    unsigned short* const sK1 = (unsigned short*)(smem + 8192);
    unsigned short* const sV0 = (unsigned short*)(smem + 16384);
    unsigned short* const sV1 = (unsigned short*)(smem + 24576);
    unsigned short* const sPB = (unsigned short*)(smem + 32768);
    unsigned short* const sQs = (unsigned short*)(smem + 16384); // overlay on V

    const int tid  = threadIdx.x;
    const int lane = tid & 63;
    const int w    = tid >> 6;
    const int lq   = lane & 15;
    const int h    = lane >> 4;
    const int l7   = lq & 7;

    int b   = blockIdx.x;
    int swz = (b & 7) * 128 + (b >> 3);
    int bh  = swz >> 5, qt = swz & 31;
    const int q0 = qt * QB;

    const float* Qh = Q + ((size_t)bh * S_LEN + q0) * D_DIM;
    const int*   Mh = M + (size_t)bh * S_LEN * S_LEN;
    const unsigned short* Kh = Kimg + (size_t)bh * NKT * 4096;
    const unsigned short* Vh = Vimg + (size_t)bh * NKT * 4096;
    float* Ah = attn_out + (size_t)bh * S_LEN * S_LEN;
    float* Ch = ctx_out  + (size_t)bh * S_LEN * D_DIM;

    // frag chunk offsets (ushort units); row&7 == lq&7 for rows jt*16+lq
    const int kf0 = ((h)     ^ l7) << 3;
    const int kf1 = ((4 + h) ^ l7) << 3;

    // ---- prologue: stage Q (scaled into log2 domain), issue K(0), mask(0) ----
    const float SC = 0.18033688011112042f;   // 0.125 * log2(e)
    {
        const int srow = tid >> 4, c4 = tid & 15;
        #pragma unroll
        for (int i = 0; i < 4; ++i) {
            int row = srow + i * 16;
            float4 v = *(const float4*)(Qh + (size_t)row * D_DIM + c4 * 4);
            us4 bq = { f2bf(v.x * SC), f2bf(v.y * SC), f2bf(v.z * SC), f2bf(v.w * SC) };
            *(us4*)(&sQs[row * 68 + c4 * 4]) = bq;
        }
    }
    #pragma unroll
    for (int i = 0; i < 2; ++i)
        gload16((const unsigned char*)Kh + w * 2048 + i * 1024 + lane * 16,
                (unsigned char*)sK0 + w * 2048 + i * 1024);

    const int* Mb = Mh + (size_t)(q0 + w * 16 + h * 4) * S_LEN + lq;
    int mfA[4][4], mfB[4][4];
    #pragma unroll
    for (int jt = 0; jt < 4; ++jt)
        #pragma unroll
        for (int r = 0; r < 4; ++r)
            mfA[jt][r] = Mb[(size_t)r * S_LEN + jt * 16];
    __syncthreads();

    bf16x8 aq0 = *(const bf16x8*)(&sQs[(w * 16 + lq) * 68 + h * 8]);
    bf16x8 aq1 = *(const bf16x8*)(&sQs[(w * 16 + lq) * 68 + 32 + h * 8]);

    // ================= pass 1 =================
    float m[4], lsum[4];
    unsigned bits[4][4];
    #pragma unroll
    for (int r = 0; r < 4; ++r) {
        m[r] = -1e30f; lsum[r] = 0.f;
        #pragma unroll
        for (int jt = 0; jt < 4; ++jt) bits[jt][r] = 0u;
    }

    auto step1 = [&](unsigned short* cur, unsigned short* nxt,
                     int (&mfU)[4][4], int (&mfN)[4][4], int kt) {
        const int ktn = (kt + 1 < NKT) ? kt + 1 : kt;
        #pragma unroll
        for (int i = 0; i < 2; ++i)
            gload16((const unsigned char*)(Kh + (size_t)ktn * 4096) + w * 2048 + i * 1024 + lane * 16,
                    (unsigned char*)nxt + w * 2048 + i * 1024);
        __builtin_amdgcn_sched_barrier(0);
        #pragma unroll
        for (int jt = 0; jt < 4; ++jt)
            #pragma unroll
            for (int r = 0; r < 4; ++r)
                mfN[jt][r] = Mb[(size_t)r * S_LEN + ktn * 64 + jt * 16];

        f32x4 acc[4];
        #pragma unroll
        for (int jt = 0; jt < 4; ++jt) {
            acc[jt] = (f32x4){0.f, 0.f, 0.f, 0.f};
            const unsigned short* kb = cur + (jt * 16 + lq) * 64;
            bf16x8 b0 = *(const bf16x8*)(kb + kf0);
            bf16x8 b1 = *(const bf16x8*)(kb + kf1);
            acc[jt] = __builtin_amdgcn_mfma_f32_16x16x32_bf16(aq0, b0, acc[jt], 0, 0, 0);
            acc[jt] = __builtin_amdgcn_mfma_f32_16x16x32_bf16(aq1, b1, acc[jt], 0, 0, 0);
        }

        float sc[4][4];
        #pragma unroll
        for (int jt = 0; jt < 4; ++jt)
            #pragma unroll
            for (int r = 0; r < 4; ++r) {
                bits[jt][r] |= (mfU[jt][r] ? 1u : 0u) << kt;
                sc[jt][r] = mfU[jt][r] ? -1e30f : acc[jt][r];
            }
        #pragma unroll
        for (int r = 0; r < 4; ++r) {
            float tm = fmaxf(fmaxf(sc[0][r], sc[1][r]), fmaxf(sc[2][r], sc[3][r]));
            float nm = fmaxf(m[r], tm);
            float su = exp2f(sc[0][r] - nm) + exp2f(sc[1][r] - nm)
                     + exp2f(sc[2][r] - nm) + exp2f(sc[3][r] - nm);
            lsum[r] = lsum[r] * exp2f(m[r] - nm) + su;
            m[r] = nm;
        }
        __syncthreads();
    };

    for (int kt = 0; kt < NKT; kt += 2) {
        step1(sK0, sK1, mfA, mfB, kt);
        step1(sK1, sK0, mfB, mfA, kt + 1);
    }

    // butterfly-combine (m,l) across the 16 lanes owning each row
    float myM[4], myIL[4];
    #pragma unroll
    for (int r = 0; r < 4; ++r) {
        float mi = m[r], li = lsum[r];
        #pragma unroll
        for (int off = 1; off < 16; off <<= 1) {
            float om = __shfl_xor(mi, off);
            float ol = __shfl_xor(li, off);
            float nm = fmaxf(mi, om);
            li = li * exp2f(mi - nm) + ol * exp2f(om - nm);
            mi = nm;
        }
        myM[r]  = mi;
        myIL[r] = (li > 0.f) ? (1.f / li) : 0.f;
    }

    // ---- pass-2 prologue: issue K(0), V(0) (V region overlaid sQ, now dead) --
    #pragma unroll
    for (int i = 0; i < 2; ++i) {
        gload16((const unsigned char*)Kh + w * 2048 + i * 1024 + lane * 16,
                (unsigned char*)sK0 + w * 2048 + i * 1024);
        gload16((const unsigned char*)Vh + w * 2048 + i * 1024 + lane * 16,
                (unsigned char*)sV0 + w * 2048 + i * 1024);
    }
    __syncthreads();

    // ================= pass 2 =================
    f32x4 ctxa[4];
    #pragma unroll
    for (int dt = 0; dt < 4; ++dt) ctxa[dt] = (f32x4){0.f, 0.f, 0.f, 0.f};

    unsigned short* const sPw = sPB + w * 1024;
    float* const Abase = Ah + (size_t)(q0 + w * 16) * S_LEN;

    auto step2 = [&](unsigned short* curK, unsigned short* curV,
                     unsigned short* nxtK, unsigned short* nxtV, int kt) {
        const int ktn = (kt + 1 < NKT) ? kt + 1 : kt;
        #pragma unroll
        for (int i = 0; i < 2; ++i) {
            gload16((const unsigned char*)(Kh + (size_t)ktn * 4096) + w * 2048 + i * 1024 + lane * 16,
                    (unsigned char*)nxtK + w * 2048 + i * 1024);
            gload16((const unsigned char*)(Vh + (size_t)ktn * 4096) + w * 2048 + i * 1024 + lane * 16,
                    (unsigned char*)nxtV + w * 2048 + i * 1024);
        }
        __builtin_amdgcn_sched_barrier(0);

        f32x4 acc[4];
        #pragma unroll
        for (int jt = 0; jt < 4; ++jt) {
            acc[jt] = (f32x4){0.f, 0.f, 0.f, 0.f};
            const unsigned short* kb = curK + (jt * 16 + lq) * 64;
            bf16x8 b0 = *(const bf16x8*)(kb + kf0);
            bf16x8 b1 = *(const bf16x8*)(kb + kf1);
            acc[jt] = __builtin_amdgcn_mfma_f32_16x16x32_bf16(aq0, b0, acc[jt], 0, 0, 0);
            acc[jt] = __builtin_amdgcn_mfma_f32_16x16x32_bf16(aq1, b1, acc[jt], 0, 0, 0);
        }

        // P -> per-wave swizzled LDS tile (bf16)
        #pragma unroll
        for (int jt = 0; jt < 4; ++jt)
            #pragma unroll
            for (int r = 0; r < 4; ++r) {
                bool msk = (bits[jt][r] >> kt) & 1u;
                float p = exp2f(acc[jt][r] - myM[r]) * myIL[r];
                p = msk ? 0.f : p;
                int row = h * 4 + r;
                sPw[row * 64 + ((((jt << 1) | (lq >> 3)) ^ (row & 7)) << 3) + l7] = f2bf(p);
            }
        asm volatile("s_waitcnt lgkmcnt(0)" ::: "memory");
        __builtin_amdgcn_sched_barrier(0);

        // coalesced attn write from sPw
        float* Aw = Abase + kt * 64;
        #pragma unroll
        for (int it = 0; it < 4; ++it) {
            int row = it * 4 + h;
            us4 pb = *(const us4*)(&sPw[row * 64 + (((lq >> 1) ^ (row & 7)) << 3) + (lq & 1) * 4]);
            float4 pf = make_float4(bf2f(pb.x), bf2f(pb.y), bf2f(pb.z), bf2f(pb.w));
            *(float4*)(Aw + (size_t)row * S_LEN + lq * 4) = pf;
        }

        // PV
        bf16x8 pa0 = *(const bf16x8*)(&sPw[lq * 64 + ((h ^ l7) << 3)]);
        bf16x8 pa1 = *(const bf16x8*)(&sPw[lq * 64 + (((4 + h) ^ l7) << 3)]);
        #pragma unroll
        for (int dt = 0; dt < 4; ++dt) {
            const unsigned short* vb = curV + (dt * 16 + lq) * 64;
            bf16x8 b0 = *(const bf16x8*)(vb + kf0);
            bf16x8 b1 = *(const bf16x8*)(vb + kf1);
            ctxa[dt] = __builtin_amdgcn_mfma_f32_16x16x32_bf16(pa0, b0, ctxa[dt], 0, 0, 0);
            ctxa[dt] = __builtin_amdgcn_mfma_f32_16x16x32_bf16(pa1, b1, ctxa[dt], 0, 0, 0);
        }
        __syncthreads();
    };

    for (int kt = 0; kt < NKT; kt += 2) {
        step2(sK0, sV0, sK1, sV1, kt);
        step2(sK1, sV1, sK0, sV0, kt + 1);
    }

    float* Crow = Ch + (size_t)(q0 + w * 16 + h * 4) * D_DIM;
    #pragma unroll
    for (int dt = 0; dt < 4; ++dt)
        #pragma unroll
        for (int r = 0; r < 4; ++r)
            Crow[(size_t)r * D_DIM + dt * 16 + lq] = ctxa[dt][r];
}

extern "C" void kernel_launch(void* const* d_in, const int* in_sizes, int n_in,
                              void* d_out, int out_size, void* d_ws, size_t ws_size,
                              hipStream_t stream)
{
    const float* Q = (const float*)d_in[0];
    const float* K = (const float*)d_in[1];
    const float* V = (const float*)d_in[2];
    const int*   M = (const int*)d_in[3];

    float* ctx  = (float*)d_out;
    float* attn = ctx + (size_t)2 * 16 * S_LEN * D_DIM;

    const size_t imgElems = (size_t)32 * NKT * 4096;      // 4.19M ushorts each
    if (ws_size < 2 * imgElems * sizeof(unsigned short)) return; // need 16 MB
    unsigned short* Kimg = (unsigned short*)d_ws;
    unsigned short* Vimg = Kimg + imgElems;

    sdpa_prep<<<dim3(1024), 256, 0, stream>>>(K, V, Kimg, Vimg);
    sdpa_main<<<dim3(1024), 256, 0, stream>>>(Q, M, Kimg, Vimg, ctx, attn);
}